// Round 16
// baseline (528.198 us; speedup 1.0000x reference)
//
#include <hip/hip_runtime.h>
#include <stdint.h>

#define N_TOK 32768
#define D_IN  512
#define H_DIM 2048
#define O_DIM 512
#define N_EXP 8
// tiles: M=128 rows of permuted tokens. sum ceil(cnt/128) <= 256+7; pad to 272 = 8 XCDs * 34
#define NTILES 272
#define TPX    34

typedef __bf16 bf16x8 __attribute__((ext_vector_type(8)));
typedef float  f32x4  __attribute__((ext_vector_type(4)));
typedef unsigned int u32x4 __attribute__((ext_vector_type(4)));

struct alignas(8) us4 { unsigned short x, y, z, w; };

#define FENCE() asm volatile("" ::: "memory")
#define BAR()   do { FENCE(); __builtin_amdgcn_s_barrier(); FENCE(); } while (0)
#define WAITV0  asm volatile("s_waitcnt vmcnt(0)" ::: "memory")

__device__ __forceinline__ unsigned short f2bf(float f) {
  union { float f; unsigned u; } v; v.f = f;
  unsigned r = v.u + 0x7FFFu + ((v.u >> 16) & 1u);  // round-to-nearest-even
  return (unsigned short)(r >> 16);
}

// async global->LDS, 16B/lane; LDS dest = wave-uniform base + lane*16 (HW)
__device__ __forceinline__ void gll16(const void* src, void* lds_dst) {
  __builtin_amdgcn_global_load_lds(
      (const __attribute__((address_space(1))) void*)src,
      (__attribute__((address_space(3))) void*)lds_dst, 16, 0, 0);
}

// ---------------- weight convert + transpose to bf16 (W1 and W2 in ONE launch) ----------------
// z=0: W1 (E,512,2048) -> W1T (E,2048,512); z=1: W2 (E,2048,512) -> W2T (E,512,2048).
__global__ void k_transpose2(const float* __restrict__ W1, unsigned short* __restrict__ W1T,
                             const float* __restrict__ W2, unsigned short* __restrict__ W2T) {
  __shared__ unsigned short tile[64][72];
  int e = blockIdx.y;
  int R = blockIdx.z ? H_DIM : D_IN;
  int C = blockIdx.z ? O_DIM : H_DIM;
  const float* src = (blockIdx.z ? W2 : W1) + (size_t)e * R * C;
  unsigned short* dst = (blockIdx.z ? W2T : W1T) + (size_t)e * R * C;
  int tilesC = C >> 6;
  int tc = (blockIdx.x % tilesC) << 6;
  int tr = (blockIdx.x / tilesC) << 6;
  int tid = threadIdx.x;
  int rq = tid >> 4;
  int cq = tid & 15;
#pragma unroll
  for (int q = 0; q < 4; ++q) {
    int r = q * 16 + rq;
    float4 v = *(const float4*)(src + (size_t)(tr + r) * C + tc + cq * 4);
    us4 b;
    b.x = f2bf(v.x); b.y = f2bf(v.y); b.z = f2bf(v.z); b.w = f2bf(v.w);
    *(us4*)&tile[r][cq * 4] = b;
  }
  __syncthreads();
#pragma unroll
  for (int q = 0; q < 4; ++q) {
    int cc = q * 16 + rq;
    int rr = cq * 4;
    us4 o;
    o.x = tile[rr + 0][cc]; o.y = tile[rr + 1][cc];
    o.z = tile[rr + 2][cc]; o.w = tile[rr + 3][cc];
    *(us4*)(dst + (size_t)(tc + cc) * R + tr + rr) = o;
  }
}

// ---------------- router (fp32) + fused x -> bf16 cast; NO atomics ----------------
__global__ void k_router(const float* __restrict__ x, const float* __restrict__ Wr,
                         const float* __restrict__ br, int* __restrict__ expert_id,
                         unsigned short* __restrict__ xbf) {
  int token = blockIdx.x * 4 + (threadIdx.x >> 6);
  int lane  = threadIdx.x & 63;
  const float* xr = x + (size_t)token * D_IN;
  float acc[N_EXP];
#pragma unroll
  for (int e = 0; e < N_EXP; ++e) acc[e] = 0.f;
#pragma unroll
  for (int j = 0; j < 2; ++j) {
    int i0 = lane * 8 + j * 4;
    float4 xv = *(const float4*)(xr + i0);
    us4 bb;
    bb.x = f2bf(xv.x); bb.y = f2bf(xv.y); bb.z = f2bf(xv.z); bb.w = f2bf(xv.w);
    *(us4*)(xbf + (size_t)token * D_IN + i0) = bb;
    float xs[4] = {xv.x, xv.y, xv.z, xv.w};
#pragma unroll
    for (int u = 0; u < 4; ++u) {
      const float4* wr = (const float4*)(Wr + (size_t)(i0 + u) * N_EXP);
      float4 w0 = wr[0], w1 = wr[1];
      acc[0] += xs[u] * w0.x; acc[1] += xs[u] * w0.y;
      acc[2] += xs[u] * w0.z; acc[3] += xs[u] * w0.w;
      acc[4] += xs[u] * w1.x; acc[5] += xs[u] * w1.y;
      acc[6] += xs[u] * w1.z; acc[7] += xs[u] * w1.w;
    }
  }
#pragma unroll
  for (int off = 32; off > 0; off >>= 1) {
#pragma unroll
    for (int e = 0; e < N_EXP; ++e) acc[e] += __shfl_xor(acc[e], off, 64);
  }
  if (lane == 0) {
    float best = acc[0] + br[0]; int bi = 0;
#pragma unroll
    for (int e = 1; e < N_EXP; ++e) {
      float v = acc[e] + br[e];
      if (v > best) { best = v; bi = e; }   // first max wins (matches top_k)
    }
    expert_id[token] = bi;
  }
}

// ---------------- count: LDS histogram ----------------
__global__ void k_count(const int* __restrict__ expert_id, int* __restrict__ counts) {
  __shared__ int lcnt[N_EXP];
  int tid = threadIdx.x;
  if (tid < N_EXP) lcnt[tid] = 0;
  __syncthreads();
  int e = expert_id[blockIdx.x * 1024 + tid];
  atomicAdd(&lcnt[e], 1);
  __syncthreads();
  if (tid < N_EXP) atomicAdd(&counts[tid], lcnt[tid]);
}

// ---------------- scan: offsets + cursors + expert-major 128-row tile table ----------------
__global__ void k_scan(const int* __restrict__ counts, int* __restrict__ offsets,
                       int* __restrict__ cursor, int2* __restrict__ table) {
  int i = threadIdx.x;   // 512 threads
  int s = 0, ts = 0, myexp = -1, myt = -1;
#pragma unroll
  for (int e = 0; e < N_EXP; ++e) {
    int c = counts[e];
    int tc = (c + 127) >> 7;
    if (i == e) { offsets[e] = s; cursor[e] = s; }
    if (i >= ts && i < ts + tc) { myexp = e; myt = i - ts; }
    s += c; ts += tc;
  }
  if (i < NTILES) table[i] = make_int2(myexp, myt);
}

// ---------------- scatter: LDS histogram, one block-atomic per expert ----------------
__global__ void k_scatter(const int* __restrict__ expert_id, int* __restrict__ cursor,
                          int* __restrict__ idx_list) {
  __shared__ int lcnt[N_EXP], lbase[N_EXP];
  int tid = threadIdx.x;
  int i = blockIdx.x * 512 + tid;
  if (tid < N_EXP) lcnt[tid] = 0;
  __syncthreads();
  int e = expert_id[i];
  int lpos = atomicAdd(&lcnt[e], 1);
  __syncthreads();
  if (tid < N_EXP) lbase[tid] = atomicAdd(&cursor[tid], lcnt[tid]);
  __syncthreads();
  idx_list[lbase[e] + lpos] = i;
}

// ========== r8-proven GEMM core: 128x128 tile, BK=64, 4 waves, SINGLE 32KB LDS buffer ==========
// 5 blocks/CU (32KB x 5 = 160KB exactly); latency hiding via inter-block overlap.
// stage -> vmcnt(0) -> bar -> mfma -> bar.

// ---------------- GEMM1: Hperm = relu(Xg @ W1T^T + b1) ----------------
__launch_bounds__(256, 5)
__global__ void k_gemm1(const unsigned short* __restrict__ xbf,
                        const unsigned short* __restrict__ W1T,   // (E, H, D) bf16
                        const float* __restrict__ b1,
                        const int* __restrict__ counts, const int* __restrict__ offsets,
                        const int2* __restrict__ table, const int* __restrict__ idx_list,
                        unsigned short* __restrict__ Hperm,       // (N_TOK, hchunk) bf16
                        int nt1, int ch, int hchunk) {
  int xcd = blockIdx.x & 7;
  int s   = blockIdx.x >> 3;
  int tile  = xcd * TPX + s / nt1;   // XCD owns a CONTIGUOUS run of tiles -> 1 expert panel in L2
  int ntile = s % nt1;
  int2 et = table[tile];
  int e = et.x;
  if (e < 0) return;
  int base   = offsets[e] + et.y * 128;
  int mvalid = min(128, counts[e] - et.y * 128);

  __shared__ __align__(16) unsigned char lds[32768];  // A @0 (16K), B @16K; epilogue bounce reuses all

  int tid = threadIdx.x, w = tid >> 6, lane = tid & 63;
  int l15 = lane & 15, l4 = lane >> 4;
  int wr = w >> 1, wc = w & 1;
  int n0 = ch * hchunk + ntile * 128;   // global H col base

  unsigned offA[4], offB[4];
#pragma unroll
  for (int q = 0; q < 4; ++q) {
    int d   = q * 4096 + w * 1024 + lane * 16;   // linear dest byte in 16KB tile
    int row = d >> 7;
    int bs  = (d & 127) ^ ((row & 7) << 4);      // inverse-swizzled source byte
    int tok = idx_list[base + min(row, mvalid - 1)];
    offA[q] = (unsigned)tok * (D_IN * 2) + bs;
    offB[q] = (unsigned)(e * H_DIM + n0 + row) * (D_IN * 2) + bs;
  }

  f32x4 acc[4][4];
#pragma unroll
  for (int a = 0; a < 4; ++a)
#pragma unroll
    for (int b = 0; b < 4; ++b) acc[a][b] = (f32x4){0.f, 0.f, 0.f, 0.f};

#define STAGE1(kstep) do {                                                   \
    unsigned kb = (unsigned)(kstep) * 128u;                                  \
    _Pragma("unroll")                                                        \
    for (int q = 0; q < 4; ++q) {                                            \
      gll16((const char*)xbf + offA[q] + kb, lds + q * 4096 + w * 1024);     \
      gll16((const char*)W1T + offB[q] + kb, lds + 16384 + q * 4096 + w * 1024); \
    }                                                                        \
  } while (0)

#define COMPUTE1() do {                                                      \
    const unsigned char* A = lds;                                            \
    const unsigned char* B = lds + 16384;                                    \
    __builtin_amdgcn_s_setprio(1);                                           \
    _Pragma("unroll")                                                        \
    for (int ks = 0; ks < 2; ++ks) {                                         \
      int kb = ks * 64 + l4 * 16;                                            \
      bf16x8 bfr[4];                                                         \
      _Pragma("unroll")                                                      \
      for (int nf = 0; nf < 4; ++nf) {                                       \
        int n = wc * 64 + nf * 16 + l15;                                     \
        bfr[nf] = *(const bf16x8*)(B + n * 128 + (kb ^ ((n & 7) << 4)));     \
      }                                                                      \
      _Pragma("unroll")                                                      \
      for (int mf = 0; mf < 4; ++mf) {                                       \
        int m = wr * 64 + mf * 16 + l15;                                     \
        bf16x8 af = *(const bf16x8*)(A + m * 128 + (kb ^ ((m & 7) << 4)));   \
        _Pragma("unroll")                                                    \
        for (int nf = 0; nf < 4; ++nf)                                       \
          acc[mf][nf] = __builtin_amdgcn_mfma_f32_16x16x32_bf16(af, bfr[nf], acc[mf][nf], 0, 0, 0); \
      }                                                                      \
    }                                                                        \
    __builtin_amdgcn_s_setprio(0);                                           \
  } while (0)

  const int NK = D_IN / 64;  // 8
  for (int t = 0; t < NK; ++t) {
    STAGE1(t);
    WAITV0;
    BAR();
    COMPUTE1();
    BAR();
  }

  // epilogue: bias+relu -> bf16 LDS bounce (128 rows x 256 B, XOR swz) -> coalesced stores
#pragma unroll
  for (int nf = 0; nf < 4; ++nf) {
    int col = wc * 64 + nf * 16 + l15;
    float bv = b1[(size_t)e * H_DIM + n0 + col];
#pragma unroll
    for (int mf = 0; mf < 4; ++mf) {
#pragma unroll
      for (int j = 0; j < 4; ++j) {
        int row = wr * 64 + mf * 16 + l4 * 4 + j;
        float v = fmaxf(acc[mf][nf][j] + bv, 0.f);
        *(unsigned short*)(lds + row * 256 + ((col * 2) ^ ((row & 7) << 4))) = f2bf(v);
      }
    }
  }
  BAR();
  {
    int row = tid >> 1;          // 0..127
    int seg = (tid & 1) * 128;   // 128B half of the 256B row
    if (row < mvalid) {
      int swz = (row & 7) << 4;
      char* gdst = (char*)Hperm + ((size_t)(base + row) * hchunk + ntile * 128) * 2 + seg;
      const unsigned char* lsrc = lds + row * 256;
#pragma unroll
      for (int i = 0; i < 8; ++i) {
        u32x4 v = *(const u32x4*)(lsrc + ((seg + i * 16) ^ swz));
        *(u32x4*)(gdst + i * 16) = v;
      }
    }
  }
#undef STAGE1
#undef COMPUTE1
}

// ---------------- GEMM2: out = Hperm @ W2T^T (+ b2) ----------------
__launch_bounds__(256, 5)
__global__ void k_gemm2(const unsigned short* __restrict__ Hperm,  // (N_TOK, hchunk) bf16
                        const unsigned short* __restrict__ W2T,    // (E, O, H) bf16
                        const float* __restrict__ b2,
                        const int* __restrict__ counts, const int* __restrict__ offsets,
                        const int2* __restrict__ table, const int* __restrict__ idx_list,
                        float* __restrict__ out,
                        int ch, int hchunk, int accumulate) {
  int xcd = blockIdx.x & 7;
  int s   = blockIdx.x >> 3;
  int tile  = xcd * TPX + (s >> 2);   // contiguous tile run per XCD
  int ntile = s & 3;
  int2 et = table[tile];
  int e = et.x;
  if (e < 0) return;
  int base   = offsets[e] + et.y * 128;
  int mvalid = min(128, counts[e] - et.y * 128);

  __shared__ __align__(16) unsigned char lds[32768];

  int tid = threadIdx.x, w = tid >> 6, lane = tid & 63;
  int l15 = lane & 15, l4 = lane >> 4;
  int wr = w >> 1, wc = w & 1;
  int o0 = ntile * 128;
  const unsigned hrow = (unsigned)hchunk * 2;

  unsigned offA[4], offB[4];
#pragma unroll
  for (int q = 0; q < 4; ++q) {
    int d   = q * 4096 + w * 1024 + lane * 16;
    int row = d >> 7;
    int bs  = (d & 127) ^ ((row & 7) << 4);
    offA[q] = (unsigned)min(base + row, N_TOK - 1) * hrow + bs;
    offB[q] = (unsigned)(e * O_DIM + o0 + row) * (H_DIM * 2) + (unsigned)ch * hchunk * 2 + bs;
  }

  f32x4 acc[4][4];
#pragma unroll
  for (int a = 0; a < 4; ++a)
#pragma unroll
    for (int b = 0; b < 4; ++b) acc[a][b] = (f32x4){0.f, 0.f, 0.f, 0.f};

#define STAGE2(kstep) do {                                                   \
    unsigned kb = (unsigned)(kstep) * 128u;                                  \
    _Pragma("unroll")                                                        \
    for (int q = 0; q < 4; ++q) {                                            \
      gll16((const char*)Hperm + offA[q] + kb, lds + q * 4096 + w * 1024);   \
      gll16((const char*)W2T   + offB[q] + kb, lds + 16384 + q * 4096 + w * 1024); \
    }                                                                        \
  } while (0)

#define COMPUTE2() do {                                                      \
    const unsigned char* A = lds;                                            \
    const unsigned char* B = lds + 16384;                                    \
    __builtin_amdgcn_s_setprio(1);                                           \
    _Pragma("unroll")                                                        \
    for (int ks = 0; ks < 2; ++ks) {                                         \
      int kb = ks * 64 + l4 * 16;                                            \
      bf16x8 bfr[4];                                                         \
      _Pragma("unroll")                                                      \
      for (int nf = 0; nf < 4; ++nf) {                                       \
        int n = wc * 64 + nf * 16 + l15;                                     \
        bfr[nf] = *(const bf16x8*)(B + n * 128 + (kb ^ ((n & 7) << 4)));     \
      }                                                                      \
      _Pragma("unroll")                                                      \
      for (int mf = 0; mf < 4; ++mf) {                                       \
        int m = wr * 64 + mf * 16 + l15;                                     \
        bf16x8 af = *(const bf16x8*)(A + m * 128 + (kb ^ ((m & 7) << 4)));   \
        _Pragma("unroll")                                                    \
        for (int nf = 0; nf < 4; ++nf)                                       \
          acc[mf][nf] = __builtin_amdgcn_mfma_f32_16x16x32_bf16(af, bfr[nf], acc[mf][nf], 0, 0, 0); \
      }                                                                      \
    }                                                                        \
    __builtin_amdgcn_s_setprio(0);                                           \
  } while (0)

  const int NK = hchunk / 64;  // 32 at hchunk=2048
  for (int t = 0; t < NK; ++t) {
    STAGE2(t);
    WAITV0;
    BAR();
    COMPUTE2();
    BAR();
  }

  // epilogue: scatter fp32 rows (64B contiguous per 16 lanes), bias on first chunk
#pragma unroll
  for (int nf = 0; nf < 4; ++nf) {
    int o = o0 + wc * 64 + nf * 16 + l15;
    float bv = b2[(size_t)e * O_DIM + o];
#pragma unroll
    for (int mf = 0; mf < 4; ++mf) {
#pragma unroll
      for (int j = 0; j < 4; ++j) {
        int row = wr * 64 + mf * 16 + l4 * 4 + j;
        if (row < mvalid) {
          int tok = idx_list[base + row];
          float* p = out + (size_t)tok * O_DIM + o;
          if (accumulate) *p = *p + acc[mf][nf][j];
          else            *p = acc[mf][nf][j] + bv;
        }
      }
    }
  }
#undef STAGE2
#undef COMPUTE2
}

// ---------------- launch ----------------
extern "C" void kernel_launch(void* const* d_in, const int* in_sizes, int n_in,
                              void* d_out, int out_size, void* d_ws, size_t ws_size,
                              hipStream_t stream) {
  const float* x  = (const float*)d_in[0];
  const float* Wr = (const float*)d_in[1];
  const float* br = (const float*)d_in[2];
  const float* W1 = (const float*)d_in[3];
  const float* b1 = (const float*)d_in[4];
  const float* W2 = (const float*)d_in[5];
  const float* b2 = (const float*)d_in[6];
  float* out = (float*)d_out;

  char* ws = (char*)d_ws;
  int*  counts    = (int*)(ws + 0);
  int*  offsets   = (int*)(ws + 64);
  int*  cursor    = (int*)(ws + 128);
  int2* table     = (int2*)(ws + 256);                 // 272*8 = 2176 B
  int*  expert_id = (int*)(ws + 4096);                 // 128 KB
  int*  idx_list  = (int*)(ws + 4096 + N_TOK * 4);     // 128 KB
  size_t off = 4096 + 2 * (size_t)N_TOK * 4;
  unsigned short* xbf = (unsigned short*)(ws + off);   // 32 MB
  off += (size_t)N_TOK * D_IN * 2;
  unsigned short* W1T = (unsigned short*)(ws + off);   // 16 MB
  off += (size_t)N_EXP * H_DIM * D_IN * 2;
  unsigned short* W2T = (unsigned short*)(ws + off);   // 16 MB
  off += (size_t)N_EXP * H_DIM * O_DIM * 2;
  unsigned short* Hperm = (unsigned short*)(ws + off);

  // largest H-chunk that fits remaining workspace (256-col floor)
  int hchunk = 2048;
  while (hchunk > 256 && off + (size_t)N_TOK * hchunk * 2 > ws_size) hchunk >>= 1;
  int nch = H_DIM / hchunk;
  int nt1 = hchunk / 128;

  hipMemsetAsync(counts, 0, 64, stream);
  k_transpose2<<<dim3(256, N_EXP, 2), 256, 0, stream>>>(W1, W1T, W2, W2T);
  k_router<<<N_TOK / 4, 256, 0, stream>>>(x, Wr, br, expert_id, xbf);
  k_count<<<N_TOK / 1024, 1024, 0, stream>>>(expert_id, counts);
  k_scan<<<1, 512, 0, stream>>>(counts, offsets, cursor, table);
  k_scatter<<<N_TOK / 512, 512, 0, stream>>>(expert_id, cursor, idx_list);

  for (int ch = 0; ch < nch; ++ch) {
    k_gemm1<<<8 * TPX * nt1, 256, 0, stream>>>(xbf, W1T, b1, counts, offsets,
                                               table, idx_list, Hperm, nt1, ch, hchunk);
    k_gemm2<<<8 * TPX * 4, 256, 0, stream>>>(Hperm, W2T, b2, counts, offsets,
                                             table, idx_list, out, ch, hchunk, ch > 0);
  }
}

// Round 17
// 310.253 us; speedup vs baseline: 1.7025x; 1.7025x over previous
//
#include <hip/hip_runtime.h>
#include <stdint.h>

#define N_TOK 32768
#define D_IN  512
#define H_DIM 2048
#define O_DIM 512
#define N_EXP 8
// gemm1 tiles: M=128. sum ceil(cnt/128) <= 256+7; pad to 272 = 8 XCDs * 34
#define NT128 272
#define TPX1  34
// gemm2 tiles: M=160. sum ceil(cnt/160) <= 213; pad to 216 = 8 XCDs * 27
#define NT160 216
#define TPX2  27

typedef __bf16 bf16x8 __attribute__((ext_vector_type(8)));
typedef float  f32x4  __attribute__((ext_vector_type(4)));
typedef unsigned int u32x4 __attribute__((ext_vector_type(4)));

struct alignas(8) us4 { unsigned short x, y, z, w; };

#define FENCE() asm volatile("" ::: "memory")
#define BAR()   do { FENCE(); __builtin_amdgcn_s_barrier(); FENCE(); } while (0)
#define WAITV0  asm volatile("s_waitcnt vmcnt(0)" ::: "memory")

__device__ __forceinline__ unsigned short f2bf(float f) {
  union { float f; unsigned u; } v; v.f = f;
  unsigned r = v.u + 0x7FFFu + ((v.u >> 16) & 1u);  // round-to-nearest-even
  return (unsigned short)(r >> 16);
}

// async global->LDS, 16B/lane; LDS dest = wave-uniform base + lane*16 (HW)
__device__ __forceinline__ void gll16(const void* src, void* lds_dst) {
  __builtin_amdgcn_global_load_lds(
      (const __attribute__((address_space(1))) void*)src,
      (__attribute__((address_space(3))) void*)lds_dst, 16, 0, 0);
}

// ---------------- weight convert + transpose to bf16 (W1 and W2 in ONE launch) ----------------
__global__ void k_transpose2(const float* __restrict__ W1, unsigned short* __restrict__ W1T,
                             const float* __restrict__ W2, unsigned short* __restrict__ W2T) {
  __shared__ unsigned short tile[64][72];
  int e = blockIdx.y;
  int R = blockIdx.z ? H_DIM : D_IN;
  int C = blockIdx.z ? O_DIM : H_DIM;
  const float* src = (blockIdx.z ? W2 : W1) + (size_t)e * R * C;
  unsigned short* dst = (blockIdx.z ? W2T : W1T) + (size_t)e * R * C;
  int tilesC = C >> 6;
  int tc = (blockIdx.x % tilesC) << 6;
  int tr = (blockIdx.x / tilesC) << 6;
  int tid = threadIdx.x;
  int rq = tid >> 4;
  int cq = tid & 15;
#pragma unroll
  for (int q = 0; q < 4; ++q) {
    int r = q * 16 + rq;
    float4 v = *(const float4*)(src + (size_t)(tr + r) * C + tc + cq * 4);
    us4 b;
    b.x = f2bf(v.x); b.y = f2bf(v.y); b.z = f2bf(v.z); b.w = f2bf(v.w);
    *(us4*)&tile[r][cq * 4] = b;
  }
  __syncthreads();
#pragma unroll
  for (int q = 0; q < 4; ++q) {
    int cc = q * 16 + rq;
    int rr = cq * 4;
    us4 o;
    o.x = tile[rr + 0][cc]; o.y = tile[rr + 1][cc];
    o.z = tile[rr + 2][cc]; o.w = tile[rr + 3][cc];
    *(us4*)(dst + (size_t)(tc + cc) * R + tr + rr) = o;
  }
}

// ---------------- router (fp32) + fused x -> bf16 cast; NO atomics ----------------
__global__ void k_router(const float* __restrict__ x, const float* __restrict__ Wr,
                         const float* __restrict__ br, int* __restrict__ expert_id,
                         unsigned short* __restrict__ xbf) {
  int token = blockIdx.x * 4 + (threadIdx.x >> 6);
  int lane  = threadIdx.x & 63;
  const float* xr = x + (size_t)token * D_IN;
  float acc[N_EXP];
#pragma unroll
  for (int e = 0; e < N_EXP; ++e) acc[e] = 0.f;
#pragma unroll
  for (int j = 0; j < 2; ++j) {
    int i0 = lane * 8 + j * 4;
    float4 xv = *(const float4*)(xr + i0);
    us4 bb;
    bb.x = f2bf(xv.x); bb.y = f2bf(xv.y); bb.z = f2bf(xv.z); bb.w = f2bf(xv.w);
    *(us4*)(xbf + (size_t)token * D_IN + i0) = bb;
    float xs[4] = {xv.x, xv.y, xv.z, xv.w};
#pragma unroll
    for (int u = 0; u < 4; ++u) {
      const float4* wr = (const float4*)(Wr + (size_t)(i0 + u) * N_EXP);
      float4 w0 = wr[0], w1 = wr[1];
      acc[0] += xs[u] * w0.x; acc[1] += xs[u] * w0.y;
      acc[2] += xs[u] * w0.z; acc[3] += xs[u] * w0.w;
      acc[4] += xs[u] * w1.x; acc[5] += xs[u] * w1.y;
      acc[6] += xs[u] * w1.z; acc[7] += xs[u] * w1.w;
    }
  }
#pragma unroll
  for (int off = 32; off > 0; off >>= 1) {
#pragma unroll
    for (int e = 0; e < N_EXP; ++e) acc[e] += __shfl_xor(acc[e], off, 64);
  }
  if (lane == 0) {
    float best = acc[0] + br[0]; int bi = 0;
#pragma unroll
    for (int e = 1; e < N_EXP; ++e) {
      float v = acc[e] + br[e];
      if (v > best) { best = v; bi = e; }   // first max wins (matches top_k)
    }
    expert_id[token] = bi;
  }
}

// ---------------- count: LDS histogram ----------------
__global__ void k_count(const int* __restrict__ expert_id, int* __restrict__ counts) {
  __shared__ int lcnt[N_EXP];
  int tid = threadIdx.x;
  if (tid < N_EXP) lcnt[tid] = 0;
  __syncthreads();
  int e = expert_id[blockIdx.x * 1024 + tid];
  atomicAdd(&lcnt[e], 1);
  __syncthreads();
  if (tid < N_EXP) atomicAdd(&counts[tid], lcnt[tid]);
}

// ---------------- scan: offsets + cursors + tile tables (M=128 and M=160) ----------------
__global__ void k_scan(const int* __restrict__ counts, int* __restrict__ offsets,
                       int* __restrict__ cursor, int2* __restrict__ table128,
                       int2* __restrict__ table160) {
  int i = threadIdx.x;   // 512 threads
  {
    int s = 0, ts = 0, myexp = -1, myt = -1;
#pragma unroll
    for (int e = 0; e < N_EXP; ++e) {
      int c = counts[e];
      int tc = (c + 127) >> 7;
      if (i == e) { offsets[e] = s; cursor[e] = s; }
      if (i >= ts && i < ts + tc) { myexp = e; myt = i - ts; }
      s += c; ts += tc;
    }
    if (i < NT128) table128[i] = make_int2(myexp, myt);
  }
  {
    int ts = 0, myexp = -1, myt = -1;
#pragma unroll
    for (int e = 0; e < N_EXP; ++e) {
      int tc = (counts[e] + 159) / 160;
      if (i >= ts && i < ts + tc) { myexp = e; myt = i - ts; }
      ts += tc;
    }
    if (i < NT160) table160[i] = make_int2(myexp, myt);
  }
}

// ---------------- scatter: LDS histogram, one block-atomic per expert ----------------
__global__ void k_scatter(const int* __restrict__ expert_id, int* __restrict__ cursor,
                          int* __restrict__ idx_list) {
  __shared__ int lcnt[N_EXP], lbase[N_EXP];
  int tid = threadIdx.x;
  int i = blockIdx.x * 512 + tid;
  if (tid < N_EXP) lcnt[tid] = 0;
  __syncthreads();
  int e = expert_id[i];
  int lpos = atomicAdd(&lcnt[e], 1);
  __syncthreads();
  if (tid < N_EXP) lbase[tid] = atomicAdd(&cursor[tid], lcnt[tid]);
  __syncthreads();
  idx_list[lbase[e] + lpos] = i;
}

// ========== r8-proven GEMM core: BK=64, 4 waves, SINGLE LDS buffer, 4 blocks/CU. ==========
// stage -> vmcnt(0) -> bar -> mfma -> bar.

// ---------------- GEMM1: Hperm = relu(Xg @ W1T^T + b1); 128x128 tile ----------------
__launch_bounds__(256, 4)
__global__ void k_gemm1(const unsigned short* __restrict__ xbf,
                        const unsigned short* __restrict__ W1T,   // (E, H, D) bf16
                        const float* __restrict__ b1,
                        const int* __restrict__ counts, const int* __restrict__ offsets,
                        const int2* __restrict__ table, const int* __restrict__ idx_list,
                        unsigned short* __restrict__ Hperm,       // (N_TOK, hchunk) bf16
                        int nt1, int ch, int hchunk) {
  int xcd = blockIdx.x & 7;
  int s   = blockIdx.x >> 3;
  int tile  = xcd * TPX1 + s / nt1;   // contiguous tile run per XCD
  int ntile = s % nt1;
  int2 et = table[tile];
  int e = et.x;
  if (e < 0) return;
  int base   = offsets[e] + et.y * 128;
  int mvalid = min(128, counts[e] - et.y * 128);

  __shared__ __align__(16) unsigned char lds[32768];  // A @0 (16K), B @16K

  int tid = threadIdx.x, w = tid >> 6, lane = tid & 63;
  int l15 = lane & 15, l4 = lane >> 4;
  int wr = w >> 1, wc = w & 1;
  int n0 = ch * hchunk + ntile * 128;

  unsigned offA[4], offB[4];
#pragma unroll
  for (int q = 0; q < 4; ++q) {
    int d   = q * 4096 + w * 1024 + lane * 16;
    int row = d >> 7;
    int bs  = (d & 127) ^ ((row & 7) << 4);
    int tok = idx_list[base + min(row, mvalid - 1)];
    offA[q] = (unsigned)tok * (D_IN * 2) + bs;
    offB[q] = (unsigned)(e * H_DIM + n0 + row) * (D_IN * 2) + bs;
  }

  f32x4 acc[4][4];
#pragma unroll
  for (int a = 0; a < 4; ++a)
#pragma unroll
    for (int b = 0; b < 4; ++b) acc[a][b] = (f32x4){0.f, 0.f, 0.f, 0.f};

#define STAGE1(kstep) do {                                                   \
    unsigned kb = (unsigned)(kstep) * 128u;                                  \
    _Pragma("unroll")                                                        \
    for (int q = 0; q < 4; ++q) {                                            \
      gll16((const char*)xbf + offA[q] + kb, lds + q * 4096 + w * 1024);     \
      gll16((const char*)W1T + offB[q] + kb, lds + 16384 + q * 4096 + w * 1024); \
    }                                                                        \
  } while (0)

#define COMPUTE1() do {                                                      \
    const unsigned char* A = lds;                                            \
    const unsigned char* B = lds + 16384;                                    \
    __builtin_amdgcn_s_setprio(1);                                           \
    _Pragma("unroll")                                                        \
    for (int ks = 0; ks < 2; ++ks) {                                         \
      int kb = ks * 64 + l4 * 16;                                            \
      bf16x8 bfr[4];                                                         \
      _Pragma("unroll")                                                      \
      for (int nf = 0; nf < 4; ++nf) {                                       \
        int n = wc * 64 + nf * 16 + l15;                                     \
        bfr[nf] = *(const bf16x8*)(B + n * 128 + (kb ^ ((n & 7) << 4)));     \
      }                                                                      \
      _Pragma("unroll")                                                      \
      for (int mf = 0; mf < 4; ++mf) {                                       \
        int m = wr * 64 + mf * 16 + l15;                                     \
        bf16x8 af = *(const bf16x8*)(A + m * 128 + (kb ^ ((m & 7) << 4)));   \
        _Pragma("unroll")                                                    \
        for (int nf = 0; nf < 4; ++nf)                                       \
          acc[mf][nf] = __builtin_amdgcn_mfma_f32_16x16x32_bf16(af, bfr[nf], acc[mf][nf], 0, 0, 0); \
      }                                                                      \
    }                                                                        \
    __builtin_amdgcn_s_setprio(0);                                           \
  } while (0)

  const int NK = D_IN / 64;  // 8
  for (int t = 0; t < NK; ++t) {
    STAGE1(t);
    WAITV0;
    BAR();
    COMPUTE1();
    BAR();
  }

  // epilogue: bias+relu -> bf16 LDS bounce (128 rows x 256 B, XOR swz) -> coalesced stores
#pragma unroll
  for (int nf = 0; nf < 4; ++nf) {
    int col = wc * 64 + nf * 16 + l15;
    float bv = b1[(size_t)e * H_DIM + n0 + col];
#pragma unroll
    for (int mf = 0; mf < 4; ++mf) {
#pragma unroll
      for (int j = 0; j < 4; ++j) {
        int row = wr * 64 + mf * 16 + l4 * 4 + j;
        float v = fmaxf(acc[mf][nf][j] + bv, 0.f);
        *(unsigned short*)(lds + row * 256 + ((col * 2) ^ ((row & 7) << 4))) = f2bf(v);
      }
    }
  }
  BAR();
  {
    int row = tid >> 1;
    int seg = (tid & 1) * 128;
    if (row < mvalid) {
      int swz = (row & 7) << 4;
      char* gdst = (char*)Hperm + ((size_t)(base + row) * hchunk + ntile * 128) * 2 + seg;
      const unsigned char* lsrc = lds + row * 256;
#pragma unroll
      for (int i = 0; i < 8; ++i) {
        u32x4 v = *(const u32x4*)(lsrc + ((seg + i * 16) ^ swz));
        *(u32x4*)(gdst + i * 16) = v;
      }
    }
  }
#undef STAGE1
#undef COMPUTE1
}

// ---------------- GEMM2: out = Hperm @ W2T^T (+ b2); 160x128 tile (single-round grid) ----------------
__launch_bounds__(256, 4)
__global__ void k_gemm2(const unsigned short* __restrict__ Hperm,  // (N_TOK, hchunk) bf16
                        const unsigned short* __restrict__ W2T,    // (E, O, H) bf16
                        const float* __restrict__ b2,
                        const int* __restrict__ counts, const int* __restrict__ offsets,
                        const int2* __restrict__ table160, const int* __restrict__ idx_list,
                        float* __restrict__ out,
                        int ch, int hchunk, int accumulate) {
  int xcd = blockIdx.x & 7;
  int s   = blockIdx.x >> 3;
  int tile  = xcd * TPX2 + (s >> 2);   // contiguous tile run per XCD
  int ntile = s & 3;
  int2 et = table160[tile];
  int e = et.x;
  if (e < 0) return;
  int base   = offsets[e] + et.y * 160;
  int mvalid = min(160, counts[e] - et.y * 160);

  __shared__ __align__(16) unsigned char lds[36864];  // A @0 (20K, 160 rows), B @20480 (16K, 128 rows)

  int tid = threadIdx.x, w = tid >> 6, lane = tid & 63;
  int l15 = lane & 15, l4 = lane >> 4;
  int wr = w >> 1, wc = w & 1;
  int o0 = ntile * 128;
  const unsigned hrow = (unsigned)hchunk * 2;

  unsigned offA[5], offB[4];
#pragma unroll
  for (int q = 0; q < 5; ++q) {
    int d   = q * 4096 + w * 1024 + lane * 16;   // dest byte in 20KB A region
    int row = d >> 7;                            // 0..159
    int bs  = (d & 127) ^ ((row & 7) << 4);
    offA[q] = (unsigned)min(base + min(row, mvalid - 1), N_TOK - 1) * hrow + bs;
  }
#pragma unroll
  for (int q = 0; q < 4; ++q) {
    int d   = q * 4096 + w * 1024 + lane * 16;
    int row = d >> 7;                            // 0..127
    int bs  = (d & 127) ^ ((row & 7) << 4);
    offB[q] = (unsigned)(e * O_DIM + o0 + row) * (H_DIM * 2) + (unsigned)ch * hchunk * 2 + bs;
  }

  f32x4 acc[5][4];
#pragma unroll
  for (int a = 0; a < 5; ++a)
#pragma unroll
    for (int b = 0; b < 4; ++b) acc[a][b] = (f32x4){0.f, 0.f, 0.f, 0.f};

#define STAGE2(kstep) do {                                                   \
    unsigned kb = (unsigned)(kstep) * 128u;                                  \
    _Pragma("unroll")                                                        \
    for (int q = 0; q < 5; ++q)                                              \
      gll16((const char*)Hperm + offA[q] + kb, lds + q * 4096 + w * 1024);   \
    _Pragma("unroll")                                                        \
    for (int q = 0; q < 4; ++q)                                              \
      gll16((const char*)W2T + offB[q] + kb, lds + 20480 + q * 4096 + w * 1024); \
  } while (0)

#define COMPUTE2() do {                                                      \
    const unsigned char* A = lds;                                            \
    const unsigned char* B = lds + 20480;                                    \
    __builtin_amdgcn_s_setprio(1);                                           \
    _Pragma("unroll")                                                        \
    for (int ks = 0; ks < 2; ++ks) {                                         \
      int kb = ks * 64 + l4 * 16;                                            \
      bf16x8 bfr[4];                                                         \
      _Pragma("unroll")                                                      \
      for (int nf = 0; nf < 4; ++nf) {                                       \
        int n = wc * 64 + nf * 16 + l15;                                     \
        bfr[nf] = *(const bf16x8*)(B + n * 128 + (kb ^ ((n & 7) << 4)));     \
      }                                                                      \
      _Pragma("unroll")                                                      \
      for (int mf = 0; mf < 5; ++mf) {                                       \
        int m = wr * 80 + mf * 16 + l15;                                     \
        bf16x8 af = *(const bf16x8*)(A + m * 128 + (kb ^ ((m & 7) << 4)));   \
        _Pragma("unroll")                                                    \
        for (int nf = 0; nf < 4; ++nf)                                       \
          acc[mf][nf] = __builtin_amdgcn_mfma_f32_16x16x32_bf16(af, bfr[nf], acc[mf][nf], 0, 0, 0); \
      }                                                                      \
    }                                                                        \
    __builtin_amdgcn_s_setprio(0);                                           \
  } while (0)

  const int NK = hchunk / 64;  // 32 at hchunk=2048
  for (int t = 0; t < NK; ++t) {
    STAGE2(t);
    WAITV0;
    BAR();
    COMPUTE2();
    BAR();
  }

  // epilogue: scatter fp32 rows (64B contiguous per 16 lanes), bias on first chunk
#pragma unroll
  for (int nf = 0; nf < 4; ++nf) {
    int o = o0 + wc * 64 + nf * 16 + l15;
    float bv = b2[(size_t)e * O_DIM + o];
#pragma unroll
    for (int mf = 0; mf < 5; ++mf) {
#pragma unroll
      for (int j = 0; j < 4; ++j) {
        int row = wr * 80 + mf * 16 + l4 * 4 + j;
        if (row < mvalid) {
          int tok = idx_list[base + row];
          float* p = out + (size_t)tok * O_DIM + o;
          if (accumulate) *p = *p + acc[mf][nf][j];
          else            *p = acc[mf][nf][j] + bv;
        }
      }
    }
  }
#undef STAGE2
#undef COMPUTE2
}

// ---------------- launch ----------------
extern "C" void kernel_launch(void* const* d_in, const int* in_sizes, int n_in,
                              void* d_out, int out_size, void* d_ws, size_t ws_size,
                              hipStream_t stream) {
  const float* x  = (const float*)d_in[0];
  const float* Wr = (const float*)d_in[1];
  const float* br = (const float*)d_in[2];
  const float* W1 = (const float*)d_in[3];
  const float* b1 = (const float*)d_in[4];
  const float* W2 = (const float*)d_in[5];
  const float* b2 = (const float*)d_in[6];
  float* out = (float*)d_out;

  char* ws = (char*)d_ws;
  int*  counts    = (int*)(ws + 0);
  int*  offsets   = (int*)(ws + 64);
  int*  cursor    = (int*)(ws + 128);
  int2* table128  = (int2*)(ws + 256);                 // 272*8 = 2176 B
  int2* table160  = (int2*)(ws + 2560);                // 216*8 = 1728 B
  int*  expert_id = (int*)(ws + 8192);                 // 128 KB
  int*  idx_list  = (int*)(ws + 8192 + N_TOK * 4);     // 128 KB
  size_t off = 8192 + 2 * (size_t)N_TOK * 4;
  unsigned short* xbf = (unsigned short*)(ws + off);   // 32 MB
  off += (size_t)N_TOK * D_IN * 2;
  unsigned short* W1T = (unsigned short*)(ws + off);   // 16 MB
  off += (size_t)N_EXP * H_DIM * D_IN * 2;
  unsigned short* W2T = (unsigned short*)(ws + off);   // 16 MB
  off += (size_t)N_EXP * H_DIM * O_DIM * 2;
  unsigned short* Hperm = (unsigned short*)(ws + off);

  // largest H-chunk that fits remaining workspace (256-col floor)
  int hchunk = 2048;
  while (hchunk > 256 && off + (size_t)N_TOK * hchunk * 2 > ws_size) hchunk >>= 1;
  int nch = H_DIM / hchunk;
  int nt1 = hchunk / 128;

  hipMemsetAsync(counts, 0, 64, stream);
  k_transpose2<<<dim3(256, N_EXP, 2), 256, 0, stream>>>(W1, W1T, W2, W2T);
  k_router<<<N_TOK / 4, 256, 0, stream>>>(x, Wr, br, expert_id, xbf);
  k_count<<<N_TOK / 1024, 1024, 0, stream>>>(expert_id, counts);
  k_scan<<<1, 512, 0, stream>>>(counts, offsets, cursor, table128, table160);
  k_scatter<<<N_TOK / 512, 512, 0, stream>>>(expert_id, cursor, idx_list);

  for (int ch = 0; ch < nch; ++ch) {
    k_gemm1<<<8 * TPX1 * nt1, 256, 0, stream>>>(xbf, W1T, b1, counts, offsets,
                                                table128, idx_list, Hperm, nt1, ch, hchunk);
    k_gemm2<<<8 * TPX2 * 4, 256, 0, stream>>>(Hperm, W2T, b2, counts, offsets,
                                              table160, idx_list, out, ch, hchunk, ch > 0);
  }
}